// Round 9
// baseline (226.360 us; speedup 1.0000x reference)
//
#include <hip/hip_runtime.h>
#include <hip/hip_bf16.h>

// B=2, T=2048, E=1024, H=16, D=64. Inputs f32 (+ int32 mask), output f32.
// Internal bf16 MFMA pipeline.
// prep: ONE dispatch = embed f32->bf16 convert + 4x weight transpose+cast
//       + mask int32 -> 1-bit bitmask (1MB, L2-resident).
// Flash: round-6 kernel verbatim (frozen; 65.6-68us band).
// qkv THIS ROUND: fused 3-way GEMM at 64-row tiles. Round-8's 128-row fused
//   kernel was 256 blocks = 1 block/CU (2 waves/SIMD) -- no second block to
//   cover the per-K-step barrier drain (m114). 64x128x3 tile -> grid (8,64)
//   = 512 blocks = 2 blocks/CU (16 waves/CU), LDS 56KB, VGPR<=128 via
//   launch_bounds(512,4). A-traffic unchanged (64MB); per-thread 7 ASYNC16
//   -> 24 MFMA. Plain grid: XCD = blockIdx.x = B-panel -> 768KB B-slice
//   L2-resident per XCD, A streams from L3.
// out GEMM: round-8 wrapper verbatim.

typedef __bf16 bf8_t  __attribute__((ext_vector_type(8)));
typedef __bf16 bf4_t  __attribute__((ext_vector_type(4)));
typedef float  f4_t   __attribute__((ext_vector_type(4)));

constexpr int Bb = 2, Tt = 2048, Hh = 16, Dd = 64;

#define ASYNC16(g, l)                                                        \
    __builtin_amdgcn_global_load_lds(                                        \
        (const __attribute__((address_space(1))) void*)(g),                  \
        (__attribute__((address_space(3))) void*)(l), 16, 0, 0)

#if __has_builtin(__builtin_amdgcn_exp2f)
#define EXP2F(x) __builtin_amdgcn_exp2f(x)
#else
#define EXP2F(x) exp2f(x)
#endif

// ---------------------------------------------------------------- prep
// blockIdx.x decode: [0,4096) transpose W (z>>10 = which matrix),
// [4096,5120) convert embed, [5120,6144) build bitmask.
__global__ __launch_bounds__(256) void prep_kernel(
    const float* __restrict__ embed, const int* __restrict__ mask,
    const float* __restrict__ w0, const float* __restrict__ w1,
    const float* __restrict__ w2, const float* __restrict__ w3,
    __bf16* __restrict__ o0, __bf16* __restrict__ o1,
    __bf16* __restrict__ o2, __bf16* __restrict__ o3,
    __bf16* __restrict__ Eb, unsigned* __restrict__ Mbits)
{
    int z = blockIdx.x;
    if (z < 4096) {
        const float* in; __bf16* out;
        switch (z >> 10) {
            case 0: in = w0; out = o0; break;
            case 1: in = w1; out = o1; break;
            case 2: in = w2; out = o2; break;
            default: in = w3; out = o3; break;
        }
        int rem = z & 1023;
        int bx = (rem & 31) * 32;      // n offset
        int by = (rem >> 5) * 32;      // k offset
        __shared__ float t[32][33];
        int x  = threadIdx.x & 31;
        int y0 = threadIdx.x >> 5;
        #pragma unroll
        for (int i = 0; i < 4; i++) {
            int y = y0 + i * 8;
            t[y][x] = in[(size_t)(by + y) * 1024 + bx + x];
        }
        __syncthreads();
        #pragma unroll
        for (int i = 0; i < 4; i++) {
            int y = y0 + i * 8;
            out[(size_t)(bx + y) * 1024 + by + x] = (__bf16)t[x][y];
        }
    } else if (z < 5120) {
        size_t base = (size_t)(z - 4096) * 4096;
        #pragma unroll
        for (int j = 0; j < 4; j++) {
            size_t i = base + j * 1024 + threadIdx.x * 4;
            float4 v = *reinterpret_cast<const float4*>(embed + i);
            bf4_t o = {(__bf16)v.x, (__bf16)v.y, (__bf16)v.z, (__bf16)v.w};
            *reinterpret_cast<bf4_t*>(Eb + i) = o;
        }
    } else {
        // word g covers mask[g*32 .. g*32+32)
        size_t g = (size_t)(z - 5120) * 256 + threadIdx.x;
        const int* mp = mask + g * 32;
        unsigned v = 0;
        #pragma unroll
        for (int i = 0; i < 8; i++) {
            int4 m4 = *reinterpret_cast<const int4*>(mp + i * 4);
            if (m4.x) v |= 1u << (i * 4 + 0);
            if (m4.y) v |= 1u << (i * 4 + 1);
            if (m4.z) v |= 1u << (i * 4 + 2);
            if (m4.w) v |= 1u << (i * 4 + 3);
        }
        Mbits[g] = v;
    }
}

// ---------------------------------------------------------------- fused QKV
// One block = 64 rows of Eb x 128 cols of Q, K and V. A staged ONCE per
// K-step; 3 B-tiles; per-thread 7 ASYNC16 -> 24 MFMA. grid (8,64):
// XCD = bx (B-panel L2-resident). 8 waves: wm = w&1 (32-row half),
// wn = w>>1 (32-col quarter).
__global__ __launch_bounds__(512, 4) void gemm_qkv_fused(
    const __bf16* __restrict__ A,
    const __bf16* __restrict__ WqT, const __bf16* __restrict__ WkT, const __bf16* __restrict__ WvT,
    const float* __restrict__ bq,  const float* __restrict__ bk,  const float* __restrict__ bv,
    __bf16* __restrict__ Qo, __bf16* __restrict__ Ko, __bf16* __restrict__ Vo)
{
    alignas(16) __shared__ __bf16 As[64 * 64];       // 8KB
    alignas(16) __shared__ __bf16 Bs[3][128 * 64];   // 48KB

    int bx = blockIdx.x;        // 0..7  (col panel; == XCD under round-robin)
    int by = blockIdx.y;        // 0..63 (row panel)

    int tid  = threadIdx.x;
    int lane = tid & 63;
    int quad = lane >> 4;
    int l16  = lane & 15;
    int wave = tid >> 6;        // 0..7
    int wm   = wave & 1;        // row half (32 rows)
    int wn   = wave >> 1;       // col quarter (32 cols)

    const __bf16* Bp[3] = {WqT, WkT, WvT};

    f4_t acc[3][2][2];
    #pragma unroll
    for (int m = 0; m < 3; m++)
        #pragma unroll
        for (int i = 0; i < 2; i++)
            #pragma unroll
            for (int j = 0; j < 2; j++)
                acc[m][i][j] = f4_t{0.f, 0.f, 0.f, 0.f};

    for (int kt = 0; kt < 1024; kt += 64) {
        {   // A: 64x64 = 512 chunks, 1 per thread
            int row = tid >> 3, j = tid & 7;
            ASYNC16(A + (size_t)(by * 64 + row) * 1024 + kt + ((j ^ (row & 7)) * 8),
                    &As[tid * 8]);
        }
        #pragma unroll
        for (int m = 0; m < 3; m++)
            #pragma unroll
            for (int i = 0; i < 2; i++) {
                int c   = tid + 512 * i;
                int row = c >> 3, j = c & 7;
                ASYNC16(Bp[m] + (size_t)(bx * 128 + row) * 1024 + kt + ((j ^ (row & 7)) * 8),
                        &Bs[m][c * 8]);
            }
        __syncthreads();

        bf8_t af[2][2];
        #pragma unroll
        for (int c = 0; c < 2; c++)
            #pragma unroll
            for (int im = 0; im < 2; im++) {
                int row = wm * 32 + im * 16 + l16;
                af[c][im] = *reinterpret_cast<const bf8_t*>(
                    &As[row * 64 + (((c * 4 + quad) ^ (row & 7)) * 8)]);
            }
        #pragma unroll
        for (int m = 0; m < 3; m++) {
            bf8_t bfr[2][2];
            #pragma unroll
            for (int c = 0; c < 2; c++)
                #pragma unroll
                for (int in_ = 0; in_ < 2; in_++) {
                    int row = wn * 32 + in_ * 16 + l16;
                    bfr[c][in_] = *reinterpret_cast<const bf8_t*>(
                        &Bs[m][row * 64 + (((c * 4 + quad) ^ (row & 7)) * 8)]);
                }
            #pragma unroll
            for (int c = 0; c < 2; c++)
                #pragma unroll
                for (int im = 0; im < 2; im++)
                    #pragma unroll
                    for (int in_ = 0; in_ < 2; in_++)
                        acc[m][im][in_] = __builtin_amdgcn_mfma_f32_16x16x32_bf16(
                            af[c][im], bfr[c][in_], acc[m][im][in_], 0, 0, 0);
        }
        __syncthreads();
    }

    // epilogue: Q -> [bh][d][t] *scale (mode 2), K -> [bh][t][d] (mode 1),
    // V -> [bh][d][t] (mode 2). All indices compile-time unrolled.
    const float QSC = 0.18033688011112042f;   // 0.125 * log2(e)
    #pragma unroll
    for (int im = 0; im < 2; im++) {
        #pragma unroll
        for (int in_ = 0; in_ < 2; in_++) {
            int gc  = bx * 128 + wn * 32 + in_ * 16 + l16;
            int gr0 = by * 64 + wm * 32 + im * 16 + quad * 4;
            int b = gr0 >> 11, t0 = gr0 & 2047;
            int h = gc >> 6,  d = gc & 63;
            // Q
            {
                float bb = bq[gc];
                bf4_t ov;
                #pragma unroll
                for (int r = 0; r < 4; r++)
                    ov[r] = (__bf16)((acc[0][im][in_][r] + bb) * QSC);
                *reinterpret_cast<bf4_t*>(
                    Qo + ((size_t)(b * Hh + h) * Dd + d) * Tt + t0) = ov;
            }
            // K (scalar [bh][t][d] stores)
            {
                float bb = bk[gc];
                #pragma unroll
                for (int r = 0; r < 4; r++)
                    Ko[((size_t)(b * Hh + h) * Tt + t0 + r) * Dd + d] =
                        (__bf16)(acc[1][im][in_][r] + bb);
            }
            // V
            {
                float bb = bv[gc];
                bf4_t ov;
                #pragma unroll
                for (int r = 0; r < 4; r++)
                    ov[r] = (__bf16)(acc[2][im][in_][r] + bb);
                *reinterpret_cast<bf4_t*>(
                    Vo + ((size_t)(b * Hh + h) * Dd + d) * Tt + t0) = ov;
            }
        }
    }
}

// ---------------------------------------------------------------- GEMM body
// round-7 structure verbatim (used by gemm_out only). mode 0: row-major f32.
template <int TM, typename OutT>
__device__ __forceinline__ void gemm_body(const __bf16* __restrict__ A,
                                          const __bf16* __restrict__ Bt,
                                          const float* __restrict__ bias,
                                          OutT* __restrict__ out,
                                          int mode, float oscale, int bx, int by)
{
    constexpr int NI = TM / 32;
    alignas(16) __shared__ __bf16 As[TM * 64];
    alignas(16) __shared__ __bf16 Bs[128 * 64];

    int tid  = threadIdx.x;
    int lane = tid & 63;
    int quad = lane >> 4;
    int l16  = lane & 15;
    int wave = tid >> 6;
    int wm   = wave >> 1, wn = wave & 1;

    f4_t acc[NI][4];
    #pragma unroll
    for (int i = 0; i < NI; i++)
        #pragma unroll
        for (int j = 0; j < 4; j++)
            acc[i][j] = f4_t{0.f, 0.f, 0.f, 0.f};

    for (int kt = 0; kt < 1024; kt += 64) {
        #pragma unroll
        for (int i = 0; i < TM / 32; i++) {
            int c   = tid + 256 * i;
            int row = c >> 3, j = c & 7;
            ASYNC16(A + (size_t)(by * TM + row) * 1024 + kt + ((j ^ (row & 7)) * 8),
                    &As[c * 8]);
        }
        #pragma unroll
        for (int i = 0; i < 4; i++) {
            int c   = tid + 256 * i;
            int row = c >> 3, j = c & 7;
            ASYNC16(Bt + (size_t)(bx * 128 + row) * 1024 + kt + ((j ^ (row & 7)) * 8),
                    &Bs[c * 8]);
        }
        __syncthreads();

        bf8_t af[2][NI], bfr[2][4];
        #pragma unroll
        for (int c = 0; c < 2; c++) {
            #pragma unroll
            for (int im = 0; im < NI; im++) {
                int row = wm * (TM / 2) + im * 16 + l16;
                af[c][im] = *reinterpret_cast<const bf8_t*>(
                    &As[row * 64 + (((c * 4 + quad) ^ (row & 7)) * 8)]);
            }
            #pragma unroll
            for (int in_ = 0; in_ < 4; in_++) {
                int row = wn * 64 + in_ * 16 + l16;
                bfr[c][in_] = *reinterpret_cast<const bf8_t*>(
                    &Bs[row * 64 + (((c * 4 + quad) ^ (row & 7)) * 8)]);
            }
        }
        #pragma unroll
        for (int c = 0; c < 2; c++)
            #pragma unroll
            for (int im = 0; im < NI; im++)
                #pragma unroll
                for (int in_ = 0; in_ < 4; in_++)
                    acc[im][in_] = __builtin_amdgcn_mfma_f32_16x16x32_bf16(
                        af[c][im], bfr[c][in_], acc[im][in_], 0, 0, 0);
        __syncthreads();
    }

    #pragma unroll
    for (int im = 0; im < NI; im++) {
        #pragma unroll
        for (int in_ = 0; in_ < 4; in_++) {
            int gc  = bx * 128 + wn * 64 + in_ * 16 + l16;
            float bb = bias[gc];
            int gr0 = by * TM + wm * (TM / 2) + im * 16 + quad * 4;
            #pragma unroll
            for (int r = 0; r < 4; r++) {
                int gr  = gr0 + r;
                float v = (acc[im][in_][r] + bb) * oscale;
                out[(size_t)gr * 1024 + gc] = (OutT)v;
            }
        }
    }
    (void)mode;
}

__global__ __launch_bounds__(256) void gemm_out_kernel(
    const __bf16* __restrict__ A, const __bf16* __restrict__ Bt,
    const float* __restrict__ bias, float* __restrict__ out)
{
    // 512 blocks: XCD j gets by-range [j*8, j*8+8).
    int lin = blockIdx.x + 8 * blockIdx.y;          // 0..511
    int swz = (lin & 7) * 64 + (lin >> 3);
    gemm_body<64, float>(A, Bt, bias, out, 0, 1.f, swz & 7, swz >> 3);
}

// ---------------------------------------------------------------- flash attn
// Round-6 kernel verbatim (frozen). grid (T/128, H, B), 512 thr = 8 waves x
// 16-row q-strips, full 64-key tiles. Dbuf LDS, one barrier/iter, reg-staged
// K/V prefetch issued after the barrier. Mask via u64 bitmask. l_i via
// ones-MFMA; setprio(1) around MFMA clusters. Q read from [bh][d][t].
__global__ __launch_bounds__(512, 4) void flash_kernel(
    const __bf16* __restrict__ Qb, const __bf16* __restrict__ Kb,
    const __bf16* __restrict__ Vb, const unsigned* __restrict__ Mbits,
    __bf16* __restrict__ Zb)
{
    alignas(16) __shared__ __bf16 Ks[2][64 * 64];   // swizzled, 8KB each
    alignas(16) __shared__ __bf16 Vs[2][64 * 64];
    alignas(16) __shared__ __bf16 Ps[8 * 16 * 72];  // per-wave P^T, 18KB

    int tid  = threadIdx.x;
    int lane = tid & 63;
    int wave = tid >> 6;
    int quad = lane >> 4;
    int l16  = lane & 15;
    int b = blockIdx.z, h = blockIdx.y;
    int bh = b * Hh + h;
    int qrow = blockIdx.x * 128 + wave * 16;

    int srow = tid >> 3, sj = tid & 7;
    const __bf16* kgp = Kb + ((size_t)bh * Tt + srow) * Dd + ((sj ^ (srow & 7)) * 8);
    const __bf16* vgp = Vb + ((size_t)bh * Dd + srow) * Tt + ((sj ^ (srow & 7)) * 8);
    const int sdst = tid * 8;

    // Q from [bh][d][t]: lane l16 = query row qrow+l16, 8 d-values per chunk.
    bf8_t qf[2];
    #pragma unroll
    for (int c = 0; c < 2; c++)
        #pragma unroll
        for (int j = 0; j < 8; j++)
            qf[c][j] = Qb[((size_t)bh * Dd + c * 32 + quad * 8 + j) * Tt
                          + qrow + l16];

    // ones-fragment for the l_i row-sum MFMA (A = all-ones 16x32 tile)
    bf8_t ones;
    #pragma unroll
    for (int i = 0; i < 8; i++) ones[i] = (__bf16)1.0f;

    // bitmask row for this lane's query: 64 words/row, u64 per 64-key tile
    const unsigned* bmp = Mbits + ((size_t)b * Tt + qrow + l16) * 64;

    f4_t lacc = f4_t{0.f, 0.f, 0.f, 0.f};
    f4_t o[4];
    #pragma unroll
    for (int d = 0; d < 4; d++) o[d] = f4_t{0.f, 0.f, 0.f, 0.f};

    __bf16* pw = Ps + wave * 16 * 72;

    // prime: tile 0 into regs
    bf8_t kreg = *reinterpret_cast<const bf8_t*>(kgp);
    bf8_t vreg = *reinterpret_cast<const bf8_t*>(vgp);
    unsigned long long mreg = *reinterpret_cast<const unsigned long long*>(bmp);

    for (int kt = 0; kt < Tt; kt += 64) {
        int par = (kt >> 6) & 1;
        *reinterpret_cast<bf8_t*>(&Ks[par][sdst]) = kreg;
        *reinterpret_cast<bf8_t*>(&Vs[par][sdst]) = vreg;
        // per-n 4-bit nibbles for this lane's quad, captured before reload
        unsigned nib[4];
        #pragma unroll
        for (int n = 0; n < 4; n++)
            nib[n] = (unsigned)(mreg >> (n * 16 + quad * 4)) & 0xFu;
        __syncthreads();

        // prefetch next tile (issued after barrier -> not drained by it)
        int ktn = (kt + 64 < Tt) ? kt + 64 : 0;
        kreg = *reinterpret_cast<const bf8_t*>(kgp + (size_t)ktn * Dd);
        vreg = *reinterpret_cast<const bf8_t*>(vgp + ktn);
        mreg = *reinterpret_cast<const unsigned long long*>(bmp + (ktn >> 5));

        // S^T = K Q^T : 4 key-subtiles x 2 d-chunks
        f4_t s[4];
        #pragma unroll
        for (int n = 0; n < 4; n++) s[n] = f4_t{0.f, 0.f, 0.f, 0.f};
        __builtin_amdgcn_s_setprio(1);
        #pragma unroll
        for (int c = 0; c < 2; c++)
            #pragma unroll
            for (int n = 0; n < 4; n++) {
                int krow = n * 16 + l16;
                bf8_t kf = *reinterpret_cast<const bf8_t*>(
                    &Ks[par][krow * 64 + (((c * 4 + quad) ^ (krow & 7)) * 8)]);
                s[n] = __builtin_amdgcn_mfma_f32_16x16x32_bf16(kf, qf[c], s[n], 0, 0, 0);
            }
        __builtin_amdgcn_s_setprio(0);

        // p = mask-bit ? exp2(s) : 0; P^T -> LDS (row-sum via MFMA below)
        #pragma unroll
        for (int n = 0; n < 4; n++) {
            bf4_t pv4;
            #pragma unroll
            for (int r = 0; r < 4; r++) {
                float p = (nib[n] & (1u << r)) ? EXP2F(s[n][r]) : 0.f;
                pv4[r] = (__bf16)p;
            }
            *reinterpret_cast<bf4_t*>(&pw[l16 * 72 + n * 16 + quad * 4]) = pv4;
        }

        // O^T += V^T @ P^T over 64 keys (2 chunks); l_i += ones @ P^T
        __builtin_amdgcn_s_setprio(1);
        #pragma unroll
        for (int c = 0; c < 2; c++) {
            bf8_t pf = *reinterpret_cast<const bf8_t*>(
                &pw[l16 * 72 + c * 32 + quad * 8]);
            lacc = __builtin_amdgcn_mfma_f32_16x16x32_bf16(ones, pf, lacc, 0, 0, 0);
            #pragma unroll
            for (int ds = 0; ds < 4; ds++) {
                int vrow = ds * 16 + l16;
                bf8_t vf = *reinterpret_cast<const bf8_t*>(
                    &Vs[par][vrow * 64 + (((c * 4 + quad) ^ (vrow & 7)) * 8)]);
                o[ds] = __builtin_amdgcn_mfma_f32_16x16x32_bf16(vf, pf, o[ds], 0, 0, 0);
            }
        }
        __builtin_amdgcn_s_setprio(0);
        // no trailing barrier: next iter writes the other buffer.
    }

    // lacc rows are all identical (ones-fragment): lacc[0] = sum_k P[k][q=l16]
    float inv = 1.f / fmaxf(lacc[0], 1e-30f);
    size_t zrow = ((size_t)b * Tt + qrow + l16) * 1024 + h * 64;
    #pragma unroll
    for (int ds = 0; ds < 4; ds++) {
        bf4_t ov;
        #pragma unroll
        for (int r = 0; r < 4; r++) ov[r] = (__bf16)(o[ds][r] * inv);
        *reinterpret_cast<bf4_t*>(Zb + zrow + ds * 16 + quad * 4) = ov;
    }
}

// ---------------------------------------------------------------- launch
extern "C" void kernel_launch(void* const* d_in, const int* in_sizes, int n_in,
                              void* d_out, int out_size, void* d_ws, size_t ws_size,
                              hipStream_t stream)
{
    (void)in_sizes; (void)n_in; (void)out_size; (void)ws_size;

    const float* embed = (const float*)d_in[0];
    const int*   mask  = (const int*)d_in[1];
    const float* Wq = (const float*)d_in[2];
    const float* bq = (const float*)d_in[3];
    const float* Wk = (const float*)d_in[4];
    const float* bk = (const float*)d_in[5];
    const float* Wv = (const float*)d_in[6];
    const float* bv = (const float*)d_in[7];
    const float* Wz = (const float*)d_in[8];
    const float* bz = (const float*)d_in[9];
    float* out = (float*)d_out;

    char* ws = (char*)d_ws;
    const size_t MB = (size_t)1024 * 1024;
    __bf16*   WqT = (__bf16*)(ws + 0 * MB);
    __bf16*   WkT = (__bf16*)(ws + 2 * MB);
    __bf16*   WvT = (__bf16*)(ws + 4 * MB);
    __bf16*   WzT = (__bf16*)(ws + 6 * MB);
    __bf16*   Eb  = (__bf16*)(ws + 8 * MB);
    __bf16*   Qb  = (__bf16*)(ws + 16 * MB);
    __bf16*   Kb  = (__bf16*)(ws + 24 * MB);
    __bf16*   Vb  = (__bf16*)(ws + 32 * MB);
    __bf16*   Zb  = (__bf16*)(ws + 40 * MB);
    unsigned* Mb  = (unsigned*)(ws + 48 * MB);   // bitmask, 1MB -> total 49MB

    prep_kernel<<<dim3(6144), 256, 0, stream>>>(embed, mask, Wq, Wk, Wv, Wz,
                                                WqT, WkT, WvT, WzT, Eb, Mb);
    gemm_qkv_fused<<<dim3(8, 64), 512, 0, stream>>>(Eb, WqT, WkT, WvT,
                                                    bq, bk, bv, Qb, Kb, Vb);
    flash_kernel<<<dim3(16, Hh, Bb), 512, 0, stream>>>(Qb, Kb, Vb, Mb, Zb);
    gemm_out_kernel<<<dim3(8, 64), 256, 0, stream>>>(Zb, WzT, bz, out);
}

// Round 10
// 221.566 us; speedup vs baseline: 1.0216x; 1.0216x over previous
//
#include <hip/hip_runtime.h>
#include <hip/hip_bf16.h>

// B=2, T=2048, E=1024, H=16, D=64. Inputs f32 (+ int32 mask), output f32.
// Internal bf16 MFMA pipeline.
// prep: ONE dispatch = embed f32->bf16 convert + 4x weight transpose+cast
//       + mask int32 -> 1-bit bitmask (1MB, L2-resident).
// qkv: round-8 fused 128-row kernel verbatim (best measured; r9's 64-row
//   variant regressed ~6us -- MFMA:stage ratio beats occupancy here).
// Flash THIS ROUND: head-grouped XCD swizzle. Old grid: XCD = id%8 = qx%8,
//   so every XCD touched all 32 heads' K/V (16MB >> 4MB L2) -> FETCH_SIZE
//   72.5MB vs 25MB unique (16x K/V re-read from HBM, ~900cy prefetch lat).
//   New: XCD j owns heads [4j,4j+4) entirely; per-XCD set = 2MB K/V + 1MB Q
//   (L2-resident) -> K/V re-reads hit L2 (~200cy). Kernel body frozen.
// out GEMM: round-8 wrapper verbatim.

typedef __bf16 bf8_t  __attribute__((ext_vector_type(8)));
typedef __bf16 bf4_t  __attribute__((ext_vector_type(4)));
typedef float  f4_t   __attribute__((ext_vector_type(4)));

constexpr int Bb = 2, Tt = 2048, Hh = 16, Dd = 64;

#define ASYNC16(g, l)                                                        \
    __builtin_amdgcn_global_load_lds(                                        \
        (const __attribute__((address_space(1))) void*)(g),                  \
        (__attribute__((address_space(3))) void*)(l), 16, 0, 0)

#if __has_builtin(__builtin_amdgcn_exp2f)
#define EXP2F(x) __builtin_amdgcn_exp2f(x)
#else
#define EXP2F(x) exp2f(x)
#endif

// ---------------------------------------------------------------- prep
// blockIdx.x decode: [0,4096) transpose W (z>>10 = which matrix),
// [4096,5120) convert embed, [5120,6144) build bitmask.
__global__ __launch_bounds__(256) void prep_kernel(
    const float* __restrict__ embed, const int* __restrict__ mask,
    const float* __restrict__ w0, const float* __restrict__ w1,
    const float* __restrict__ w2, const float* __restrict__ w3,
    __bf16* __restrict__ o0, __bf16* __restrict__ o1,
    __bf16* __restrict__ o2, __bf16* __restrict__ o3,
    __bf16* __restrict__ Eb, unsigned* __restrict__ Mbits)
{
    int z = blockIdx.x;
    if (z < 4096) {
        const float* in; __bf16* out;
        switch (z >> 10) {
            case 0: in = w0; out = o0; break;
            case 1: in = w1; out = o1; break;
            case 2: in = w2; out = o2; break;
            default: in = w3; out = o3; break;
        }
        int rem = z & 1023;
        int bx = (rem & 31) * 32;      // n offset
        int by = (rem >> 5) * 32;      // k offset
        __shared__ float t[32][33];
        int x  = threadIdx.x & 31;
        int y0 = threadIdx.x >> 5;
        #pragma unroll
        for (int i = 0; i < 4; i++) {
            int y = y0 + i * 8;
            t[y][x] = in[(size_t)(by + y) * 1024 + bx + x];
        }
        __syncthreads();
        #pragma unroll
        for (int i = 0; i < 4; i++) {
            int y = y0 + i * 8;
            out[(size_t)(bx + y) * 1024 + by + x] = (__bf16)t[x][y];
        }
    } else if (z < 5120) {
        size_t base = (size_t)(z - 4096) * 4096;
        #pragma unroll
        for (int j = 0; j < 4; j++) {
            size_t i = base + j * 1024 + threadIdx.x * 4;
            float4 v = *reinterpret_cast<const float4*>(embed + i);
            bf4_t o = {(__bf16)v.x, (__bf16)v.y, (__bf16)v.z, (__bf16)v.w};
            *reinterpret_cast<bf4_t*>(Eb + i) = o;
        }
    } else {
        // word g covers mask[g*32 .. g*32+32)
        size_t g = (size_t)(z - 5120) * 256 + threadIdx.x;
        const int* mp = mask + g * 32;
        unsigned v = 0;
        #pragma unroll
        for (int i = 0; i < 8; i++) {
            int4 m4 = *reinterpret_cast<const int4*>(mp + i * 4);
            if (m4.x) v |= 1u << (i * 4 + 0);
            if (m4.y) v |= 1u << (i * 4 + 1);
            if (m4.z) v |= 1u << (i * 4 + 2);
            if (m4.w) v |= 1u << (i * 4 + 3);
        }
        Mbits[g] = v;
    }
}

// ---------------------------------------------------------------- fused QKV
// Round-8 kernel verbatim. One block = 128 rows of Eb x 128 cols of Q, K
// and V. A staged ONCE per K-step; 3 B-tiles; 8 ASYNC16 -> 48 MFMA.
__global__ __launch_bounds__(512, 2) void gemm_qkv_fused(
    const __bf16* __restrict__ A,
    const __bf16* __restrict__ WqT, const __bf16* __restrict__ WkT, const __bf16* __restrict__ WvT,
    const float* __restrict__ bq,  const float* __restrict__ bk,  const float* __restrict__ bv,
    __bf16* __restrict__ Qo, __bf16* __restrict__ Ko, __bf16* __restrict__ Vo)
{
    alignas(16) __shared__ __bf16 As[128 * 64];      // 16KB
    alignas(16) __shared__ __bf16 Bs[3][128 * 64];   // 48KB

    // XCD-bijective swizzle: XCD j = lin&7 gets contiguous by-range.
    int lin = blockIdx.x;                 // 0..255
    int swz = (lin & 7) * 32 + (lin >> 3);
    int bx = swz & 7, by = swz >> 3;

    int tid  = threadIdx.x;
    int lane = tid & 63;
    int quad = lane >> 4;
    int l16  = lane & 15;
    int wave = tid >> 6;        // 0..7
    int wm   = wave & 3;        // row quarter (32 rows)
    int wn   = wave >> 2;       // col half (64 cols)

    const __bf16* Bp[3] = {WqT, WkT, WvT};

    f4_t acc[3][2][4];
    #pragma unroll
    for (int m = 0; m < 3; m++)
        #pragma unroll
        for (int i = 0; i < 2; i++)
            #pragma unroll
            for (int j = 0; j < 4; j++)
                acc[m][i][j] = f4_t{0.f, 0.f, 0.f, 0.f};

    for (int kt = 0; kt < 1024; kt += 64) {
        #pragma unroll
        for (int i = 0; i < 2; i++) {
            int c   = tid + 512 * i;
            int row = c >> 3, j = c & 7;
            ASYNC16(A + (size_t)(by * 128 + row) * 1024 + kt + ((j ^ (row & 7)) * 8),
                    &As[c * 8]);
        }
        #pragma unroll
        for (int m = 0; m < 3; m++)
            #pragma unroll
            for (int i = 0; i < 2; i++) {
                int c   = tid + 512 * i;
                int row = c >> 3, j = c & 7;
                ASYNC16(Bp[m] + (size_t)(bx * 128 + row) * 1024 + kt + ((j ^ (row & 7)) * 8),
                        &Bs[m][c * 8]);
            }
        __syncthreads();

        bf8_t af[2][2];
        #pragma unroll
        for (int c = 0; c < 2; c++)
            #pragma unroll
            for (int im = 0; im < 2; im++) {
                int row = wm * 32 + im * 16 + l16;
                af[c][im] = *reinterpret_cast<const bf8_t*>(
                    &As[row * 64 + (((c * 4 + quad) ^ (row & 7)) * 8)]);
            }
        #pragma unroll
        for (int m = 0; m < 3; m++) {
            bf8_t bfr[2][4];
            #pragma unroll
            for (int c = 0; c < 2; c++)
                #pragma unroll
                for (int in_ = 0; in_ < 4; in_++) {
                    int row = wn * 64 + in_ * 16 + l16;
                    bfr[c][in_] = *reinterpret_cast<const bf8_t*>(
                        &Bs[m][row * 64 + (((c * 4 + quad) ^ (row & 7)) * 8)]);
                }
            #pragma unroll
            for (int c = 0; c < 2; c++)
                #pragma unroll
                for (int im = 0; im < 2; im++)
                    #pragma unroll
                    for (int in_ = 0; in_ < 4; in_++)
                        acc[m][im][in_] = __builtin_amdgcn_mfma_f32_16x16x32_bf16(
                            af[c][im], bfr[c][in_], acc[m][im][in_], 0, 0, 0);
        }
        __syncthreads();
    }

    // epilogue: Q -> [bh][d][t] *scale (mode 2), K -> [bh][t][d] (mode 1),
    // V -> [bh][d][t] (mode 2). All indices compile-time unrolled.
    const float QSC = 0.18033688011112042f;   // 0.125 * log2(e)
    #pragma unroll
    for (int im = 0; im < 2; im++) {
        #pragma unroll
        for (int in_ = 0; in_ < 4; in_++) {
            int gc  = bx * 128 + wn * 64 + in_ * 16 + l16;
            int gr0 = by * 128 + wm * 32 + im * 16 + quad * 4;
            int b = gr0 >> 11, t0 = gr0 & 2047;
            int h = gc >> 6,  d = gc & 63;
            // Q
            {
                float bb = bq[gc];
                bf4_t ov;
                #pragma unroll
                for (int r = 0; r < 4; r++)
                    ov[r] = (__bf16)((acc[0][im][in_][r] + bb) * QSC);
                *reinterpret_cast<bf4_t*>(
                    Qo + ((size_t)(b * Hh + h) * Dd + d) * Tt + t0) = ov;
            }
            // K (scalar [bh][t][d] stores)
            {
                float bb = bk[gc];
                #pragma unroll
                for (int r = 0; r < 4; r++)
                    Ko[((size_t)(b * Hh + h) * Tt + t0 + r) * Dd + d] =
                        (__bf16)(acc[1][im][in_][r] + bb);
            }
            // V
            {
                float bb = bv[gc];
                bf4_t ov;
                #pragma unroll
                for (int r = 0; r < 4; r++)
                    ov[r] = (__bf16)(acc[2][im][in_][r] + bb);
                *reinterpret_cast<bf4_t*>(
                    Vo + ((size_t)(b * Hh + h) * Dd + d) * Tt + t0) = ov;
            }
        }
    }
}

// ---------------------------------------------------------------- GEMM body
// round-7 structure verbatim (used by gemm_out only). mode 0: row-major f32.
template <int TM, typename OutT>
__device__ __forceinline__ void gemm_body(const __bf16* __restrict__ A,
                                          const __bf16* __restrict__ Bt,
                                          const float* __restrict__ bias,
                                          OutT* __restrict__ out,
                                          int mode, float oscale, int bx, int by)
{
    constexpr int NI = TM / 32;
    alignas(16) __shared__ __bf16 As[TM * 64];
    alignas(16) __shared__ __bf16 Bs[128 * 64];

    int tid  = threadIdx.x;
    int lane = tid & 63;
    int quad = lane >> 4;
    int l16  = lane & 15;
    int wave = tid >> 6;
    int wm   = wave >> 1, wn = wave & 1;

    f4_t acc[NI][4];
    #pragma unroll
    for (int i = 0; i < NI; i++)
        #pragma unroll
        for (int j = 0; j < 4; j++)
            acc[i][j] = f4_t{0.f, 0.f, 0.f, 0.f};

    for (int kt = 0; kt < 1024; kt += 64) {
        #pragma unroll
        for (int i = 0; i < TM / 32; i++) {
            int c   = tid + 256 * i;
            int row = c >> 3, j = c & 7;
            ASYNC16(A + (size_t)(by * TM + row) * 1024 + kt + ((j ^ (row & 7)) * 8),
                    &As[c * 8]);
        }
        #pragma unroll
        for (int i = 0; i < 4; i++) {
            int c   = tid + 256 * i;
            int row = c >> 3, j = c & 7;
            ASYNC16(Bt + (size_t)(bx * 128 + row) * 1024 + kt + ((j ^ (row & 7)) * 8),
                    &Bs[c * 8]);
        }
        __syncthreads();

        bf8_t af[2][NI], bfr[2][4];
        #pragma unroll
        for (int c = 0; c < 2; c++) {
            #pragma unroll
            for (int im = 0; im < NI; im++) {
                int row = wm * (TM / 2) + im * 16 + l16;
                af[c][im] = *reinterpret_cast<const bf8_t*>(
                    &As[row * 64 + (((c * 4 + quad) ^ (row & 7)) * 8)]);
            }
            #pragma unroll
            for (int in_ = 0; in_ < 4; in_++) {
                int row = wn * 64 + in_ * 16 + l16;
                bfr[c][in_] = *reinterpret_cast<const bf8_t*>(
                    &Bs[row * 64 + (((c * 4 + quad) ^ (row & 7)) * 8)]);
            }
        }
        #pragma unroll
        for (int c = 0; c < 2; c++)
            #pragma unroll
            for (int im = 0; im < NI; im++)
                #pragma unroll
                for (int in_ = 0; in_ < 4; in_++)
                    acc[im][in_] = __builtin_amdgcn_mfma_f32_16x16x32_bf16(
                        af[c][im], bfr[c][in_], acc[im][in_], 0, 0, 0);
        __syncthreads();
    }

    #pragma unroll
    for (int im = 0; im < NI; im++) {
        #pragma unroll
        for (int in_ = 0; in_ < 4; in_++) {
            int gc  = bx * 128 + wn * 64 + in_ * 16 + l16;
            float bb = bias[gc];
            int gr0 = by * TM + wm * (TM / 2) + im * 16 + quad * 4;
            #pragma unroll
            for (int r = 0; r < 4; r++) {
                int gr  = gr0 + r;
                float v = (acc[im][in_][r] + bb) * oscale;
                out[(size_t)gr * 1024 + gc] = (OutT)v;
            }
        }
    }
    (void)mode;
}

__global__ __launch_bounds__(256) void gemm_out_kernel(
    const __bf16* __restrict__ A, const __bf16* __restrict__ Bt,
    const float* __restrict__ bias, float* __restrict__ out)
{
    // 512 blocks: XCD j gets by-range [j*8, j*8+8).
    int lin = blockIdx.x + 8 * blockIdx.y;          // 0..511
    int swz = (lin & 7) * 64 + (lin >> 3);
    gemm_body<64, float>(A, Bt, bias, out, 0, 1.f, swz & 7, swz >> 3);
}

// ---------------------------------------------------------------- flash attn
// Body frozen (round-6). THIS ROUND: 1D grid (512) with head-grouped XCD
// decode -- XCD j = id&7 owns heads [4j,4j+4): per-XCD K/V+Q working set
// ~3MB (L2-resident) vs old qx%8 mapping where every XCD touched all 32
// heads (16MB, thrashed). 512 thr = 8 waves x 16-row q-strips, 64-key
// tiles, dbuf LDS, reg prefetch, u64 bitmask, ones-MFMA l_i, setprio.
__global__ __launch_bounds__(512, 4) void flash_kernel(
    const __bf16* __restrict__ Qb, const __bf16* __restrict__ Kb,
    const __bf16* __restrict__ Vb, const unsigned* __restrict__ Mbits,
    __bf16* __restrict__ Zb)
{
    alignas(16) __shared__ __bf16 Ks[2][64 * 64];   // swizzled, 8KB each
    alignas(16) __shared__ __bf16 Vs[2][64 * 64];
    alignas(16) __shared__ __bf16 Ps[8 * 16 * 72];  // per-wave P^T, 18KB

    int tid  = threadIdx.x;
    int lane = tid & 63;
    int wave = tid >> 6;
    int quad = lane >> 4;
    int l16  = lane & 15;

    // head-grouped XCD decode: xcd = id&7 -> heads [4*xcd, 4*xcd+4)
    int id  = blockIdx.x;           // 0..511
    int xcd = id & 7;
    int idx = id >> 3;              // 0..63
    int hb  = xcd * 4 + (idx >> 4); // 0..31
    int qx  = idx & 15;
    int b = hb >> 4, h = hb & 15;
    int bh = hb;
    int qrow = qx * 128 + wave * 16;

    int srow = tid >> 3, sj = tid & 7;
    const __bf16* kgp = Kb + ((size_t)bh * Tt + srow) * Dd + ((sj ^ (srow & 7)) * 8);
    const __bf16* vgp = Vb + ((size_t)bh * Dd + srow) * Tt + ((sj ^ (srow & 7)) * 8);
    const int sdst = tid * 8;

    // Q from [bh][d][t]: lane l16 = query row qrow+l16, 8 d-values per chunk.
    bf8_t qf[2];
    #pragma unroll
    for (int c = 0; c < 2; c++)
        #pragma unroll
        for (int j = 0; j < 8; j++)
            qf[c][j] = Qb[((size_t)bh * Dd + c * 32 + quad * 8 + j) * Tt
                          + qrow + l16];

    // ones-fragment for the l_i row-sum MFMA (A = all-ones 16x32 tile)
    bf8_t ones;
    #pragma unroll
    for (int i = 0; i < 8; i++) ones[i] = (__bf16)1.0f;

    // bitmask row for this lane's query: 64 words/row, u64 per 64-key tile
    const unsigned* bmp = Mbits + ((size_t)b * Tt + qrow + l16) * 64;

    f4_t lacc = f4_t{0.f, 0.f, 0.f, 0.f};
    f4_t o[4];
    #pragma unroll
    for (int d = 0; d < 4; d++) o[d] = f4_t{0.f, 0.f, 0.f, 0.f};

    __bf16* pw = Ps + wave * 16 * 72;

    // prime: tile 0 into regs
    bf8_t kreg = *reinterpret_cast<const bf8_t*>(kgp);
    bf8_t vreg = *reinterpret_cast<const bf8_t*>(vgp);
    unsigned long long mreg = *reinterpret_cast<const unsigned long long*>(bmp);

    for (int kt = 0; kt < Tt; kt += 64) {
        int par = (kt >> 6) & 1;
        *reinterpret_cast<bf8_t*>(&Ks[par][sdst]) = kreg;
        *reinterpret_cast<bf8_t*>(&Vs[par][sdst]) = vreg;
        // per-n 4-bit nibbles for this lane's quad, captured before reload
        unsigned nib[4];
        #pragma unroll
        for (int n = 0; n < 4; n++)
            nib[n] = (unsigned)(mreg >> (n * 16 + quad * 4)) & 0xFu;
        __syncthreads();

        // prefetch next tile (issued after barrier -> not drained by it)
        int ktn = (kt + 64 < Tt) ? kt + 64 : 0;
        kreg = *reinterpret_cast<const bf8_t*>(kgp + (size_t)ktn * Dd);
        vreg = *reinterpret_cast<const bf8_t*>(vgp + ktn);
        mreg = *reinterpret_cast<const unsigned long long*>(bmp + (ktn >> 5));

        // S^T = K Q^T : 4 key-subtiles x 2 d-chunks
        f4_t s[4];
        #pragma unroll
        for (int n = 0; n < 4; n++) s[n] = f4_t{0.f, 0.f, 0.f, 0.f};
        __builtin_amdgcn_s_setprio(1);
        #pragma unroll
        for (int c = 0; c < 2; c++)
            #pragma unroll
            for (int n = 0; n < 4; n++) {
                int krow = n * 16 + l16;
                bf8_t kf = *reinterpret_cast<const bf8_t*>(
                    &Ks[par][krow * 64 + (((c * 4 + quad) ^ (krow & 7)) * 8)]);
                s[n] = __builtin_amdgcn_mfma_f32_16x16x32_bf16(kf, qf[c], s[n], 0, 0, 0);
            }
        __builtin_amdgcn_s_setprio(0);

        // p = mask-bit ? exp2(s) : 0; P^T -> LDS (row-sum via MFMA below)
        #pragma unroll
        for (int n = 0; n < 4; n++) {
            bf4_t pv4;
            #pragma unroll
            for (int r = 0; r < 4; r++) {
                float p = (nib[n] & (1u << r)) ? EXP2F(s[n][r]) : 0.f;
                pv4[r] = (__bf16)p;
            }
            *reinterpret_cast<bf4_t*>(&pw[l16 * 72 + n * 16 + quad * 4]) = pv4;
        }

        // O^T += V^T @ P^T over 64 keys (2 chunks); l_i += ones @ P^T
        __builtin_amdgcn_s_setprio(1);
        #pragma unroll
        for (int c = 0; c < 2; c++) {
            bf8_t pf = *reinterpret_cast<const bf8_t*>(
                &pw[l16 * 72 + c * 32 + quad * 8]);
            lacc = __builtin_amdgcn_mfma_f32_16x16x32_bf16(ones, pf, lacc, 0, 0, 0);
            #pragma unroll
            for (int ds = 0; ds < 4; ds++) {
                int vrow = ds * 16 + l16;
                bf8_t vf = *reinterpret_cast<const bf8_t*>(
                    &Vs[par][vrow * 64 + (((c * 4 + quad) ^ (vrow & 7)) * 8)]);
                o[ds] = __builtin_amdgcn_mfma_f32_16x16x32_bf16(vf, pf, o[ds], 0, 0, 0);
            }
        }
        __builtin_amdgcn_s_setprio(0);
        // no trailing barrier: next iter writes the other buffer.
    }

    // lacc rows are all identical (ones-fragment): lacc[0] = sum_k P[k][q=l16]
    float inv = 1.f / fmaxf(lacc[0], 1e-30f);
    size_t zrow = ((size_t)b * Tt + qrow + l16) * 1024 + h * 64;
    #pragma unroll
    for (int ds = 0; ds < 4; ds++) {
        bf4_t ov;
        #pragma unroll
        for (int r = 0; r < 4; r++) ov[r] = (__bf16)(o[ds][r] * inv);
        *reinterpret_cast<bf4_t*>(Zb + zrow + ds * 16 + quad * 4) = ov;
    }
}

// ---------------------------------------------------------------- launch
extern "C" void kernel_launch(void* const* d_in, const int* in_sizes, int n_in,
                              void* d_out, int out_size, void* d_ws, size_t ws_size,
                              hipStream_t stream)
{
    (void)in_sizes; (void)n_in; (void)out_size; (void)ws_size;

    const float* embed = (const float*)d_in[0];
    const int*   mask  = (const int*)d_in[1];
    const float* Wq = (const float*)d_in[2];
    const float* bq = (const float*)d_in[3];
    const float* Wk = (const float*)d_in[4];
    const float* bk = (const float*)d_in[5];
    const float* Wv = (const float*)d_in[6];
    const float* bv = (const float*)d_in[7];
    const float* Wz = (const float*)d_in[8];
    const float* bz = (const float*)d_in[9];
    float* out = (float*)d_out;

    char* ws = (char*)d_ws;
    const size_t MB = (size_t)1024 * 1024;
    __bf16*   WqT = (__bf16*)(ws + 0 * MB);
    __bf16*   WkT = (__bf16*)(ws + 2 * MB);
    __bf16*   WvT = (__bf16*)(ws + 4 * MB);
    __bf16*   WzT = (__bf16*)(ws + 6 * MB);
    __bf16*   Eb  = (__bf16*)(ws + 8 * MB);
    __bf16*   Qb  = (__bf16*)(ws + 16 * MB);
    __bf16*   Kb  = (__bf16*)(ws + 24 * MB);
    __bf16*   Vb  = (__bf16*)(ws + 32 * MB);
    __bf16*   Zb  = (__bf16*)(ws + 40 * MB);
    unsigned* Mb  = (unsigned*)(ws + 48 * MB);   // bitmask, 1MB -> total 49MB

    prep_kernel<<<dim3(6144), 256, 0, stream>>>(embed, mask, Wq, Wk, Wv, Wz,
                                                WqT, WkT, WvT, WzT, Eb, Mb);
    gemm_qkv_fused<<<dim3(256), 512, 0, stream>>>(Eb, WqT, WkT, WvT,
                                                  bq, bk, bv, Qb, Kb, Vb);
    flash_kernel<<<dim3(512), 512, 0, stream>>>(Qb, Kb, Vb, Mb, Zb);
    gemm_out_kernel<<<dim3(8, 64), 256, 0, stream>>>(Zb, WzT, bz, out);
}

// Round 11
// 216.604 us; speedup vs baseline: 1.0450x; 1.0229x over previous
//
#include <hip/hip_runtime.h>
#include <hip/hip_bf16.h>

// B=2, T=2048, E=1024, H=16, D=64. Inputs f32 (+ int32 mask), output f32.
// Internal bf16 MFMA pipeline.
// prep: ONE dispatch = embed f32->bf16 convert + 4x weight transpose+cast
//       + mask int32 -> 1-bit bitmask (1MB, L2-resident).
// Flash: frozen (round-10): head-grouped XCD decode (FETCH 72.5->14.4MB
//   confirmed), 8-wave q-strips, dbuf, bitmask, ones-MFMA l_i, setprio.
// qkv THIS ROUND: T3/T4 counted-vmcnt double-buffer. At 1 block/CU the
//   __syncthreads vmcnt(0) drain has no other block to cover it (m114) --
//   every K-step exposes the full 8-load staging latency. New loop:
//   STAGE(t+1 -> buf^1); vmcnt(8) [waits only PREVIOUS tile's loads, which
//   had a full iter to land]; s_barrier; compute buf[t]; lgkmcnt(0);
//   s_barrier. Same 2 barriers/iter, stage latency crosses them. LDS 128KB
//   dbuf (m201 precedent). Race audit: per-wave vmcnt(8)+barrier => all
//   waves' t-1 loads complete before any read; end barrier after lgkm(0)
//   => no read outlives into next iter's overwrite.
// out GEMM: round-8 wrapper verbatim.

typedef __bf16 bf8_t  __attribute__((ext_vector_type(8)));
typedef __bf16 bf4_t  __attribute__((ext_vector_type(4)));
typedef float  f4_t   __attribute__((ext_vector_type(4)));

constexpr int Bb = 2, Tt = 2048, Hh = 16, Dd = 64;

#define ASYNC16(g, l)                                                        \
    __builtin_amdgcn_global_load_lds(                                        \
        (const __attribute__((address_space(1))) void*)(g),                  \
        (__attribute__((address_space(3))) void*)(l), 16, 0, 0)

#if __has_builtin(__builtin_amdgcn_exp2f)
#define EXP2F(x) __builtin_amdgcn_exp2f(x)
#else
#define EXP2F(x) exp2f(x)
#endif

// ---------------------------------------------------------------- prep
// blockIdx.x decode: [0,4096) transpose W (z>>10 = which matrix),
// [4096,5120) convert embed, [5120,6144) build bitmask.
__global__ __launch_bounds__(256) void prep_kernel(
    const float* __restrict__ embed, const int* __restrict__ mask,
    const float* __restrict__ w0, const float* __restrict__ w1,
    const float* __restrict__ w2, const float* __restrict__ w3,
    __bf16* __restrict__ o0, __bf16* __restrict__ o1,
    __bf16* __restrict__ o2, __bf16* __restrict__ o3,
    __bf16* __restrict__ Eb, unsigned* __restrict__ Mbits)
{
    int z = blockIdx.x;
    if (z < 4096) {
        const float* in; __bf16* out;
        switch (z >> 10) {
            case 0: in = w0; out = o0; break;
            case 1: in = w1; out = o1; break;
            case 2: in = w2; out = o2; break;
            default: in = w3; out = o3; break;
        }
        int rem = z & 1023;
        int bx = (rem & 31) * 32;      // n offset
        int by = (rem >> 5) * 32;      // k offset
        __shared__ float t[32][33];
        int x  = threadIdx.x & 31;
        int y0 = threadIdx.x >> 5;
        #pragma unroll
        for (int i = 0; i < 4; i++) {
            int y = y0 + i * 8;
            t[y][x] = in[(size_t)(by + y) * 1024 + bx + x];
        }
        __syncthreads();
        #pragma unroll
        for (int i = 0; i < 4; i++) {
            int y = y0 + i * 8;
            out[(size_t)(bx + y) * 1024 + by + x] = (__bf16)t[x][y];
        }
    } else if (z < 5120) {
        size_t base = (size_t)(z - 4096) * 4096;
        #pragma unroll
        for (int j = 0; j < 4; j++) {
            size_t i = base + j * 1024 + threadIdx.x * 4;
            float4 v = *reinterpret_cast<const float4*>(embed + i);
            bf4_t o = {(__bf16)v.x, (__bf16)v.y, (__bf16)v.z, (__bf16)v.w};
            *reinterpret_cast<bf4_t*>(Eb + i) = o;
        }
    } else {
        // word g covers mask[g*32 .. g*32+32)
        size_t g = (size_t)(z - 5120) * 256 + threadIdx.x;
        const int* mp = mask + g * 32;
        unsigned v = 0;
        #pragma unroll
        for (int i = 0; i < 8; i++) {
            int4 m4 = *reinterpret_cast<const int4*>(mp + i * 4);
            if (m4.x) v |= 1u << (i * 4 + 0);
            if (m4.y) v |= 1u << (i * 4 + 1);
            if (m4.z) v |= 1u << (i * 4 + 2);
            if (m4.w) v |= 1u << (i * 4 + 3);
        }
        Mbits[g] = v;
    }
}

// ---------------------------------------------------------------- fused QKV
// One block = 128 rows of Eb x 128 cols of Q, K and V. A staged ONCE per
// K-step; 3 B-tiles; 8 ASYNC16 -> 48 MFMA. Double-buffered with counted
// vmcnt(8) + raw barriers (T3/T4): staging latency hidden across barriers.
__global__ __launch_bounds__(512, 2) void gemm_qkv_fused(
    const __bf16* __restrict__ A,
    const __bf16* __restrict__ WqT, const __bf16* __restrict__ WkT, const __bf16* __restrict__ WvT,
    const float* __restrict__ bq,  const float* __restrict__ bk,  const float* __restrict__ bv,
    __bf16* __restrict__ Qo, __bf16* __restrict__ Ko, __bf16* __restrict__ Vo)
{
    alignas(16) __shared__ __bf16 As[2][128 * 64];      // 32KB
    alignas(16) __shared__ __bf16 Bs[2][3][128 * 64];   // 96KB

    // XCD-bijective swizzle: XCD j = lin&7 gets contiguous by-range.
    int lin = blockIdx.x;                 // 0..255
    int swz = (lin & 7) * 32 + (lin >> 3);
    int bx = swz & 7, by = swz >> 3;

    int tid  = threadIdx.x;
    int lane = tid & 63;
    int quad = lane >> 4;
    int l16  = lane & 15;
    int wave = tid >> 6;        // 0..7
    int wm   = wave & 3;        // row quarter (32 rows)
    int wn   = wave >> 2;       // col half (64 cols)

    const __bf16* Bp[3] = {WqT, WkT, WvT};

    // per-thread staging coordinates (2 chunks of each 8192-elem tile)
    const int c0 = tid,        r0 = c0 >> 3, j0 = c0 & 7;
    const int c1 = tid + 512,  r1 = c1 >> 3, j1 = c1 & 7;

    f4_t acc[3][2][4];
    #pragma unroll
    for (int m = 0; m < 3; m++)
        #pragma unroll
        for (int i = 0; i < 2; i++)
            #pragma unroll
            for (int j = 0; j < 4; j++)
                acc[m][i][j] = f4_t{0.f, 0.f, 0.f, 0.f};

    auto STAGE = [&](int kt, int pb) {
        ASYNC16(A + (size_t)(by * 128 + r0) * 1024 + kt + ((j0 ^ (r0 & 7)) * 8),
                &As[pb][c0 * 8]);
        ASYNC16(A + (size_t)(by * 128 + r1) * 1024 + kt + ((j1 ^ (r1 & 7)) * 8),
                &As[pb][c1 * 8]);
        #pragma unroll
        for (int m = 0; m < 3; m++) {
            ASYNC16(Bp[m] + (size_t)(bx * 128 + r0) * 1024 + kt + ((j0 ^ (r0 & 7)) * 8),
                    &Bs[pb][m][c0 * 8]);
            ASYNC16(Bp[m] + (size_t)(bx * 128 + r1) * 1024 + kt + ((j1 ^ (r1 & 7)) * 8),
                    &Bs[pb][m][c1 * 8]);
        }
    };

    auto COMPUTE = [&](int pb) {
        bf8_t af[2][2];
        #pragma unroll
        for (int c = 0; c < 2; c++)
            #pragma unroll
            for (int im = 0; im < 2; im++) {
                int row = wm * 32 + im * 16 + l16;
                af[c][im] = *reinterpret_cast<const bf8_t*>(
                    &As[pb][row * 64 + (((c * 4 + quad) ^ (row & 7)) * 8)]);
            }
        #pragma unroll
        for (int m = 0; m < 3; m++) {
            bf8_t bfr[2][4];
            #pragma unroll
            for (int c = 0; c < 2; c++)
                #pragma unroll
                for (int in_ = 0; in_ < 4; in_++) {
                    int row = wn * 64 + in_ * 16 + l16;
                    bfr[c][in_] = *reinterpret_cast<const bf8_t*>(
                        &Bs[pb][m][row * 64 + (((c * 4 + quad) ^ (row & 7)) * 8)]);
                }
            #pragma unroll
            for (int c = 0; c < 2; c++)
                #pragma unroll
                for (int im = 0; im < 2; im++)
                    #pragma unroll
                    for (int in_ = 0; in_ < 4; in_++)
                        acc[m][im][in_] = __builtin_amdgcn_mfma_f32_16x16x32_bf16(
                            af[c][im], bfr[c][in_], acc[m][im][in_], 0, 0, 0);
        }
    };

    // prologue: tile 0 -> buf0, full drain
    STAGE(0, 0);
    asm volatile("s_waitcnt vmcnt(0)" ::: "memory");
    __builtin_amdgcn_s_barrier();
    __builtin_amdgcn_sched_barrier(0);

    for (int t = 0; t < 15; ++t) {
        int cur = t & 1;
        STAGE((t + 1) * 64, cur ^ 1);               // 8 loads, not drained
        asm volatile("s_waitcnt vmcnt(8)" ::: "memory");  // prev tile's done
        __builtin_amdgcn_s_barrier();
        __builtin_amdgcn_sched_barrier(0);
        COMPUTE(cur);
        asm volatile("s_waitcnt lgkmcnt(0)" ::: "memory");
        __builtin_amdgcn_s_barrier();               // reads done before overwrite
        __builtin_amdgcn_sched_barrier(0);
    }
    // last tile (t=15, buf1): staged at t=14
    asm volatile("s_waitcnt vmcnt(0)" ::: "memory");
    __builtin_amdgcn_s_barrier();
    __builtin_amdgcn_sched_barrier(0);
    COMPUTE(1);

    // epilogue: Q -> [bh][d][t] *scale (mode 2), K -> [bh][t][d] (mode 1),
    // V -> [bh][d][t] (mode 2). All indices compile-time unrolled.
    const float QSC = 0.18033688011112042f;   // 0.125 * log2(e)
    #pragma unroll
    for (int im = 0; im < 2; im++) {
        #pragma unroll
        for (int in_ = 0; in_ < 4; in_++) {
            int gc  = bx * 128 + wn * 64 + in_ * 16 + l16;
            int gr0 = by * 128 + wm * 32 + im * 16 + quad * 4;
            int b = gr0 >> 11, t0 = gr0 & 2047;
            int h = gc >> 6,  d = gc & 63;
            // Q
            {
                float bb = bq[gc];
                bf4_t ov;
                #pragma unroll
                for (int r = 0; r < 4; r++)
                    ov[r] = (__bf16)((acc[0][im][in_][r] + bb) * QSC);
                *reinterpret_cast<bf4_t*>(
                    Qo + ((size_t)(b * Hh + h) * Dd + d) * Tt + t0) = ov;
            }
            // K (scalar [bh][t][d] stores)
            {
                float bb = bk[gc];
                #pragma unroll
                for (int r = 0; r < 4; r++)
                    Ko[((size_t)(b * Hh + h) * Tt + t0 + r) * Dd + d] =
                        (__bf16)(acc[1][im][in_][r] + bb);
            }
            // V
            {
                float bb = bv[gc];
                bf4_t ov;
                #pragma unroll
                for (int r = 0; r < 4; r++)
                    ov[r] = (__bf16)(acc[2][im][in_][r] + bb);
                *reinterpret_cast<bf4_t*>(
                    Vo + ((size_t)(b * Hh + h) * Dd + d) * Tt + t0) = ov;
            }
        }
    }
}

// ---------------------------------------------------------------- GEMM body
// round-7 structure verbatim (used by gemm_out only). mode 0: row-major f32.
template <int TM, typename OutT>
__device__ __forceinline__ void gemm_body(const __bf16* __restrict__ A,
                                          const __bf16* __restrict__ Bt,
                                          const float* __restrict__ bias,
                                          OutT* __restrict__ out,
                                          int mode, float oscale, int bx, int by)
{
    constexpr int NI = TM / 32;
    alignas(16) __shared__ __bf16 As[TM * 64];
    alignas(16) __shared__ __bf16 Bs[128 * 64];

    int tid  = threadIdx.x;
    int lane = tid & 63;
    int quad = lane >> 4;
    int l16  = lane & 15;
    int wave = tid >> 6;
    int wm   = wave >> 1, wn = wave & 1;

    f4_t acc[NI][4];
    #pragma unroll
    for (int i = 0; i < NI; i++)
        #pragma unroll
        for (int j = 0; j < 4; j++)
            acc[i][j] = f4_t{0.f, 0.f, 0.f, 0.f};

    for (int kt = 0; kt < 1024; kt += 64) {
        #pragma unroll
        for (int i = 0; i < TM / 32; i++) {
            int c   = tid + 256 * i;
            int row = c >> 3, j = c & 7;
            ASYNC16(A + (size_t)(by * TM + row) * 1024 + kt + ((j ^ (row & 7)) * 8),
                    &As[c * 8]);
        }
        #pragma unroll
        for (int i = 0; i < 4; i++) {
            int c   = tid + 256 * i;
            int row = c >> 3, j = c & 7;
            ASYNC16(Bt + (size_t)(bx * 128 + row) * 1024 + kt + ((j ^ (row & 7)) * 8),
                    &Bs[c * 8]);
        }
        __syncthreads();

        bf8_t af[2][NI], bfr[2][4];
        #pragma unroll
        for (int c = 0; c < 2; c++) {
            #pragma unroll
            for (int im = 0; im < NI; im++) {
                int row = wm * (TM / 2) + im * 16 + l16;
                af[c][im] = *reinterpret_cast<const bf8_t*>(
                    &As[row * 64 + (((c * 4 + quad) ^ (row & 7)) * 8)]);
            }
            #pragma unroll
            for (int in_ = 0; in_ < 4; in_++) {
                int row = wn * 64 + in_ * 16 + l16;
                bfr[c][in_] = *reinterpret_cast<const bf8_t*>(
                    &Bs[row * 64 + (((c * 4 + quad) ^ (row & 7)) * 8)]);
            }
        }
        #pragma unroll
        for (int c = 0; c < 2; c++)
            #pragma unroll
            for (int im = 0; im < NI; im++)
                #pragma unroll
                for (int in_ = 0; in_ < 4; in_++)
                    acc[im][in_] = __builtin_amdgcn_mfma_f32_16x16x32_bf16(
                        af[c][im], bfr[c][in_], acc[im][in_], 0, 0, 0);
        __syncthreads();
    }

    #pragma unroll
    for (int im = 0; im < NI; im++) {
        #pragma unroll
        for (int in_ = 0; in_ < 4; in_++) {
            int gc  = bx * 128 + wn * 64 + in_ * 16 + l16;
            float bb = bias[gc];
            int gr0 = by * TM + wm * (TM / 2) + im * 16 + quad * 4;
            #pragma unroll
            for (int r = 0; r < 4; r++) {
                int gr  = gr0 + r;
                float v = (acc[im][in_][r] + bb) * oscale;
                out[(size_t)gr * 1024 + gc] = (OutT)v;
            }
        }
    }
    (void)mode;
}

__global__ __launch_bounds__(256) void gemm_out_kernel(
    const __bf16* __restrict__ A, const __bf16* __restrict__ Bt,
    const float* __restrict__ bias, float* __restrict__ out)
{
    // 512 blocks: XCD j gets by-range [j*8, j*8+8).
    int lin = blockIdx.x + 8 * blockIdx.y;          // 0..511
    int swz = (lin & 7) * 64 + (lin >> 3);
    gemm_body<64, float>(A, Bt, bias, out, 0, 1.f, swz & 7, swz >> 3);
}

// ---------------------------------------------------------------- flash attn
// Frozen (round-10). 1D grid (512), head-grouped XCD decode: XCD j = id&7
// owns heads [4j,4j+4) -> per-XCD K/V+Q ~3MB L2-resident (FETCH 14.4MB).
// 512 thr = 8 waves x 16-row q-strips, 64-key tiles, dbuf LDS, reg
// prefetch, u64 bitmask, ones-MFMA l_i, setprio.
__global__ __launch_bounds__(512, 4) void flash_kernel(
    const __bf16* __restrict__ Qb, const __bf16* __restrict__ Kb,
    const __bf16* __restrict__ Vb, const unsigned* __restrict__ Mbits,
    __bf16* __restrict__ Zb)
{
    alignas(16) __shared__ __bf16 Ks[2][64 * 64];   // swizzled, 8KB each
    alignas(16) __shared__ __bf16 Vs[2][64 * 64];
    alignas(16) __shared__ __bf16 Ps[8 * 16 * 72];  // per-wave P^T, 18KB

    int tid  = threadIdx.x;
    int lane = tid & 63;
    int wave = tid >> 6;
    int quad = lane >> 4;
    int l16  = lane & 15;

    // head-grouped XCD decode: xcd = id&7 -> heads [4*xcd, 4*xcd+4)
    int id  = blockIdx.x;           // 0..511
    int xcd = id & 7;
    int idx = id >> 3;              // 0..63
    int hb  = xcd * 4 + (idx >> 4); // 0..31
    int qx  = idx & 15;
    int b = hb >> 4, h = hb & 15;
    int bh = hb;
    int qrow = qx * 128 + wave * 16;

    int srow = tid >> 3, sj = tid & 7;
    const __bf16* kgp = Kb + ((size_t)bh * Tt + srow) * Dd + ((sj ^ (srow & 7)) * 8);
    const __bf16* vgp = Vb + ((size_t)bh * Dd + srow) * Tt + ((sj ^ (srow & 7)) * 8);
    const int sdst = tid * 8;

    // Q from [bh][d][t]: lane l16 = query row qrow+l16, 8 d-values per chunk.
    bf8_t qf[2];
    #pragma unroll
    for (int c = 0; c < 2; c++)
        #pragma unroll
        for (int j = 0; j < 8; j++)
            qf[c][j] = Qb[((size_t)bh * Dd + c * 32 + quad * 8 + j) * Tt
                          + qrow + l16];

    // ones-fragment for the l_i row-sum MFMA (A = all-ones 16x32 tile)
    bf8_t ones;
    #pragma unroll
    for (int i = 0; i < 8; i++) ones[i] = (__bf16)1.0f;

    // bitmask row for this lane's query: 64 words/row, u64 per 64-key tile
    const unsigned* bmp = Mbits + ((size_t)b * Tt + qrow + l16) * 64;

    f4_t lacc = f4_t{0.f, 0.f, 0.f, 0.f};
    f4_t o[4];
    #pragma unroll
    for (int d = 0; d < 4; d++) o[d] = f4_t{0.f, 0.f, 0.f, 0.f};

    __bf16* pw = Ps + wave * 16 * 72;

    // prime: tile 0 into regs
    bf8_t kreg = *reinterpret_cast<const bf8_t*>(kgp);
    bf8_t vreg = *reinterpret_cast<const bf8_t*>(vgp);
    unsigned long long mreg = *reinterpret_cast<const unsigned long long*>(bmp);

    for (int kt = 0; kt < Tt; kt += 64) {
        int par = (kt >> 6) & 1;
        *reinterpret_cast<bf8_t*>(&Ks[par][sdst]) = kreg;
        *reinterpret_cast<bf8_t*>(&Vs[par][sdst]) = vreg;
        // per-n 4-bit nibbles for this lane's quad, captured before reload
        unsigned nib[4];
        #pragma unroll
        for (int n = 0; n < 4; n++)
            nib[n] = (unsigned)(mreg >> (n * 16 + quad * 4)) & 0xFu;
        __syncthreads();

        // prefetch next tile (issued after barrier -> not drained by it)
        int ktn = (kt + 64 < Tt) ? kt + 64 : 0;
        kreg = *reinterpret_cast<const bf8_t*>(kgp + (size_t)ktn * Dd);
        vreg = *reinterpret_cast<const bf8_t*>(vgp + ktn);
        mreg = *reinterpret_cast<const unsigned long long*>(bmp + (ktn >> 5));

        // S^T = K Q^T : 4 key-subtiles x 2 d-chunks
        f4_t s[4];
        #pragma unroll
        for (int n = 0; n < 4; n++) s[n] = f4_t{0.f, 0.f, 0.f, 0.f};
        __builtin_amdgcn_s_setprio(1);
        #pragma unroll
        for (int c = 0; c < 2; c++)
            #pragma unroll
            for (int n = 0; n < 4; n++) {
                int krow = n * 16 + l16;
                bf8_t kf = *reinterpret_cast<const bf8_t*>(
                    &Ks[par][krow * 64 + (((c * 4 + quad) ^ (krow & 7)) * 8)]);
                s[n] = __builtin_amdgcn_mfma_f32_16x16x32_bf16(kf, qf[c], s[n], 0, 0, 0);
            }
        __builtin_amdgcn_s_setprio(0);

        // p = mask-bit ? exp2(s) : 0; P^T -> LDS (row-sum via MFMA below)
        #pragma unroll
        for (int n = 0; n < 4; n++) {
            bf4_t pv4;
            #pragma unroll
            for (int r = 0; r < 4; r++) {
                float p = (nib[n] & (1u << r)) ? EXP2F(s[n][r]) : 0.f;
                pv4[r] = (__bf16)p;
            }
            *reinterpret_cast<bf4_t*>(&pw[l16 * 72 + n * 16 + quad * 4]) = pv4;
        }

        // O^T += V^T @ P^T over 64 keys (2 chunks); l_i += ones @ P^T
        __builtin_amdgcn_s_setprio(1);
        #pragma unroll
        for (int c = 0; c < 2; c++) {
            bf8_t pf = *reinterpret_cast<const bf8_t*>(
                &pw[l16 * 72 + c * 32 + quad * 8]);
            lacc = __builtin_amdgcn_mfma_f32_16x16x32_bf16(ones, pf, lacc, 0, 0, 0);
            #pragma unroll
            for (int ds = 0; ds < 4; ds++) {
                int vrow = ds * 16 + l16;
                bf8_t vf = *reinterpret_cast<const bf8_t*>(
                    &Vs[par][vrow * 64 + (((c * 4 + quad) ^ (vrow & 7)) * 8)]);
                o[ds] = __builtin_amdgcn_mfma_f32_16x16x32_bf16(vf, pf, o[ds], 0, 0, 0);
            }
        }
        __builtin_amdgcn_s_setprio(0);
        // no trailing barrier: next iter writes the other buffer.
    }

    // lacc rows are all identical (ones-fragment): lacc[0] = sum_k P[k][q=l16]
    float inv = 1.f / fmaxf(lacc[0], 1e-30f);
    size_t zrow = ((size_t)b * Tt + qrow + l16) * 1024 + h * 64;
    #pragma unroll
    for (int ds = 0; ds < 4; ds++) {
        bf4_t ov;
        #pragma unroll
        for (int r = 0; r < 4; r++) ov[r] = (__bf16)(o[ds][r] * inv);
        *reinterpret_cast<bf4_t*>(Zb + zrow + ds * 16 + quad * 4) = ov;
    }
}

// ---------------------------------------------------------------- launch
extern "C" void kernel_launch(void* const* d_in, const int* in_sizes, int n_in,
                              void* d_out, int out_size, void* d_ws, size_t ws_size,
                              hipStream_t stream)
{
    (void)in_sizes; (void)n_in; (void)out_size; (void)ws_size;

    const float* embed = (const float*)d_in[0];
    const int*   mask  = (const int*)d_in[1];
    const float* Wq = (const float*)d_in[2];
    const float* bq = (const float*)d_in[3];
    const float* Wk = (const float*)d_in[4];
    const float* bk = (const float*)d_in[5];
    const float* Wv = (const float*)d_in[6];
    const float* bv = (const float*)d_in[7];
    const float* Wz = (const float*)d_in[8];
    const float* bz = (const float*)d_in[9];
    float* out = (float*)d_out;

    char* ws = (char*)d_ws;
    const size_t MB = (size_t)1024 * 1024;
    __bf16*   WqT = (__bf16*)(ws + 0 * MB);
    __bf16*   WkT = (__bf16*)(ws + 2 * MB);
    __bf16*   WvT = (__bf16*)(ws + 4 * MB);
    __bf16*   WzT = (__bf16*)(ws + 6 * MB);
    __bf16*   Eb  = (__bf16*)(ws + 8 * MB);
    __bf16*   Qb  = (__bf16*)(ws + 16 * MB);
    __bf16*   Kb  = (__bf16*)(ws + 24 * MB);
    __bf16*   Vb  = (__bf16*)(ws + 32 * MB);
    __bf16*   Zb  = (__bf16*)(ws + 40 * MB);
    unsigned* Mb  = (unsigned*)(ws + 48 * MB);   // bitmask, 1MB -> total 49MB

    prep_kernel<<<dim3(6144), 256, 0, stream>>>(embed, mask, Wq, Wk, Wv, Wz,
                                                WqT, WkT, WvT, WzT, Eb, Mb);
    gemm_qkv_fused<<<dim3(256), 512, 0, stream>>>(Eb, WqT, WkT, WvT,
                                                  bq, bk, bv, Qb, Kb, Vb);
    flash_kernel<<<dim3(512), 512, 0, stream>>>(Qb, Kb, Vb, Mb, Zb);
    gemm_out_kernel<<<dim3(8, 64), 256, 0, stream>>>(Zb, WzT, bz, out);
}

// Round 12
// 215.642 us; speedup vs baseline: 1.0497x; 1.0045x over previous
//
#include <hip/hip_runtime.h>
#include <hip/hip_bf16.h>

// B=2, T=2048, E=1024, H=16, D=64. Inputs f32 (+ int32 mask), output f32.
// Internal bf16 MFMA pipeline.
// prep: ONE dispatch = embed f32->bf16 convert + 4x weight transpose+cast
//       + mask int32 -> 1-bit bitmask (1MB, L2-resident).
// Flash: frozen (round-10): head-grouped XCD decode (FETCH 72.5->14.4MB),
//   8-wave q-strips, dbuf, bitmask, ones-MFMA l_i, setprio.
// qkv: frozen (round-11): fused 128-row, counted-vmcnt(8) dbuf -- confirmed
//   +10% (total 221.6 -> 216.6).
// out GEMM THIS ROUND: same T3/T4 counted-vmcnt dbuf pattern transferred.
//   64x128 tile, dbuf LDS 48KB, 6 loads/iter -> vmcnt(6), raw barriers +
//   sched_barrier fences, identical loop shape to the verified qkv loop.

typedef __bf16 bf8_t  __attribute__((ext_vector_type(8)));
typedef __bf16 bf4_t  __attribute__((ext_vector_type(4)));
typedef float  f4_t   __attribute__((ext_vector_type(4)));

constexpr int Bb = 2, Tt = 2048, Hh = 16, Dd = 64;

#define ASYNC16(g, l)                                                        \
    __builtin_amdgcn_global_load_lds(                                        \
        (const __attribute__((address_space(1))) void*)(g),                  \
        (__attribute__((address_space(3))) void*)(l), 16, 0, 0)

#if __has_builtin(__builtin_amdgcn_exp2f)
#define EXP2F(x) __builtin_amdgcn_exp2f(x)
#else
#define EXP2F(x) exp2f(x)
#endif

// ---------------------------------------------------------------- prep
// blockIdx.x decode: [0,4096) transpose W (z>>10 = which matrix),
// [4096,5120) convert embed, [5120,6144) build bitmask.
__global__ __launch_bounds__(256) void prep_kernel(
    const float* __restrict__ embed, const int* __restrict__ mask,
    const float* __restrict__ w0, const float* __restrict__ w1,
    const float* __restrict__ w2, const float* __restrict__ w3,
    __bf16* __restrict__ o0, __bf16* __restrict__ o1,
    __bf16* __restrict__ o2, __bf16* __restrict__ o3,
    __bf16* __restrict__ Eb, unsigned* __restrict__ Mbits)
{
    int z = blockIdx.x;
    if (z < 4096) {
        const float* in; __bf16* out;
        switch (z >> 10) {
            case 0: in = w0; out = o0; break;
            case 1: in = w1; out = o1; break;
            case 2: in = w2; out = o2; break;
            default: in = w3; out = o3; break;
        }
        int rem = z & 1023;
        int bx = (rem & 31) * 32;      // n offset
        int by = (rem >> 5) * 32;      // k offset
        __shared__ float t[32][33];
        int x  = threadIdx.x & 31;
        int y0 = threadIdx.x >> 5;
        #pragma unroll
        for (int i = 0; i < 4; i++) {
            int y = y0 + i * 8;
            t[y][x] = in[(size_t)(by + y) * 1024 + bx + x];
        }
        __syncthreads();
        #pragma unroll
        for (int i = 0; i < 4; i++) {
            int y = y0 + i * 8;
            out[(size_t)(bx + y) * 1024 + by + x] = (__bf16)t[x][y];
        }
    } else if (z < 5120) {
        size_t base = (size_t)(z - 4096) * 4096;
        #pragma unroll
        for (int j = 0; j < 4; j++) {
            size_t i = base + j * 1024 + threadIdx.x * 4;
            float4 v = *reinterpret_cast<const float4*>(embed + i);
            bf4_t o = {(__bf16)v.x, (__bf16)v.y, (__bf16)v.z, (__bf16)v.w};
            *reinterpret_cast<bf4_t*>(Eb + i) = o;
        }
    } else {
        // word g covers mask[g*32 .. g*32+32)
        size_t g = (size_t)(z - 5120) * 256 + threadIdx.x;
        const int* mp = mask + g * 32;
        unsigned v = 0;
        #pragma unroll
        for (int i = 0; i < 8; i++) {
            int4 m4 = *reinterpret_cast<const int4*>(mp + i * 4);
            if (m4.x) v |= 1u << (i * 4 + 0);
            if (m4.y) v |= 1u << (i * 4 + 1);
            if (m4.z) v |= 1u << (i * 4 + 2);
            if (m4.w) v |= 1u << (i * 4 + 3);
        }
        Mbits[g] = v;
    }
}

// ---------------------------------------------------------------- fused QKV
// Frozen (round-11). One block = 128 rows of Eb x 128 cols of Q, K and V.
// A staged ONCE per K-step; 3 B-tiles; 8 ASYNC16 -> 48 MFMA. Counted
// vmcnt(8) dbuf: staging latency hidden across barriers.
__global__ __launch_bounds__(512, 2) void gemm_qkv_fused(
    const __bf16* __restrict__ A,
    const __bf16* __restrict__ WqT, const __bf16* __restrict__ WkT, const __bf16* __restrict__ WvT,
    const float* __restrict__ bq,  const float* __restrict__ bk,  const float* __restrict__ bv,
    __bf16* __restrict__ Qo, __bf16* __restrict__ Ko, __bf16* __restrict__ Vo)
{
    alignas(16) __shared__ __bf16 As[2][128 * 64];      // 32KB
    alignas(16) __shared__ __bf16 Bs[2][3][128 * 64];   // 96KB

    // XCD-bijective swizzle: XCD j = lin&7 gets contiguous by-range.
    int lin = blockIdx.x;                 // 0..255
    int swz = (lin & 7) * 32 + (lin >> 3);
    int bx = swz & 7, by = swz >> 3;

    int tid  = threadIdx.x;
    int lane = tid & 63;
    int quad = lane >> 4;
    int l16  = lane & 15;
    int wave = tid >> 6;        // 0..7
    int wm   = wave & 3;        // row quarter (32 rows)
    int wn   = wave >> 2;       // col half (64 cols)

    const __bf16* Bp[3] = {WqT, WkT, WvT};

    // per-thread staging coordinates (2 chunks of each 8192-elem tile)
    const int c0 = tid,        r0 = c0 >> 3, j0 = c0 & 7;
    const int c1 = tid + 512,  r1 = c1 >> 3, j1 = c1 & 7;

    f4_t acc[3][2][4];
    #pragma unroll
    for (int m = 0; m < 3; m++)
        #pragma unroll
        for (int i = 0; i < 2; i++)
            #pragma unroll
            for (int j = 0; j < 4; j++)
                acc[m][i][j] = f4_t{0.f, 0.f, 0.f, 0.f};

    auto STAGE = [&](int kt, int pb) {
        ASYNC16(A + (size_t)(by * 128 + r0) * 1024 + kt + ((j0 ^ (r0 & 7)) * 8),
                &As[pb][c0 * 8]);
        ASYNC16(A + (size_t)(by * 128 + r1) * 1024 + kt + ((j1 ^ (r1 & 7)) * 8),
                &As[pb][c1 * 8]);
        #pragma unroll
        for (int m = 0; m < 3; m++) {
            ASYNC16(Bp[m] + (size_t)(bx * 128 + r0) * 1024 + kt + ((j0 ^ (r0 & 7)) * 8),
                    &Bs[pb][m][c0 * 8]);
            ASYNC16(Bp[m] + (size_t)(bx * 128 + r1) * 1024 + kt + ((j1 ^ (r1 & 7)) * 8),
                    &Bs[pb][m][c1 * 8]);
        }
    };

    auto COMPUTE = [&](int pb) {
        bf8_t af[2][2];
        #pragma unroll
        for (int c = 0; c < 2; c++)
            #pragma unroll
            for (int im = 0; im < 2; im++) {
                int row = wm * 32 + im * 16 + l16;
                af[c][im] = *reinterpret_cast<const bf8_t*>(
                    &As[pb][row * 64 + (((c * 4 + quad) ^ (row & 7)) * 8)]);
            }
        #pragma unroll
        for (int m = 0; m < 3; m++) {
            bf8_t bfr[2][4];
            #pragma unroll
            for (int c = 0; c < 2; c++)
                #pragma unroll
                for (int in_ = 0; in_ < 4; in_++) {
                    int row = wn * 64 + in_ * 16 + l16;
                    bfr[c][in_] = *reinterpret_cast<const bf8_t*>(
                        &Bs[pb][m][row * 64 + (((c * 4 + quad) ^ (row & 7)) * 8)]);
                }
            #pragma unroll
            for (int c = 0; c < 2; c++)
                #pragma unroll
                for (int im = 0; im < 2; im++)
                    #pragma unroll
                    for (int in_ = 0; in_ < 4; in_++)
                        acc[m][im][in_] = __builtin_amdgcn_mfma_f32_16x16x32_bf16(
                            af[c][im], bfr[c][in_], acc[m][im][in_], 0, 0, 0);
        }
    };

    // prologue: tile 0 -> buf0, full drain
    STAGE(0, 0);
    asm volatile("s_waitcnt vmcnt(0)" ::: "memory");
    __builtin_amdgcn_s_barrier();
    __builtin_amdgcn_sched_barrier(0);

    for (int t = 0; t < 15; ++t) {
        int cur = t & 1;
        STAGE((t + 1) * 64, cur ^ 1);               // 8 loads, not drained
        asm volatile("s_waitcnt vmcnt(8)" ::: "memory");  // prev tile's done
        __builtin_amdgcn_s_barrier();
        __builtin_amdgcn_sched_barrier(0);
        COMPUTE(cur);
        asm volatile("s_waitcnt lgkmcnt(0)" ::: "memory");
        __builtin_amdgcn_s_barrier();               // reads done before overwrite
        __builtin_amdgcn_sched_barrier(0);
    }
    // last tile (t=15, buf1): staged at t=14
    asm volatile("s_waitcnt vmcnt(0)" ::: "memory");
    __builtin_amdgcn_s_barrier();
    __builtin_amdgcn_sched_barrier(0);
    COMPUTE(1);

    // epilogue: Q -> [bh][d][t] *scale (mode 2), K -> [bh][t][d] (mode 1),
    // V -> [bh][d][t] (mode 2). All indices compile-time unrolled.
    const float QSC = 0.18033688011112042f;   // 0.125 * log2(e)
    #pragma unroll
    for (int im = 0; im < 2; im++) {
        #pragma unroll
        for (int in_ = 0; in_ < 4; in_++) {
            int gc  = bx * 128 + wn * 64 + in_ * 16 + l16;
            int gr0 = by * 128 + wm * 32 + im * 16 + quad * 4;
            int b = gr0 >> 11, t0 = gr0 & 2047;
            int h = gc >> 6,  d = gc & 63;
            // Q
            {
                float bb = bq[gc];
                bf4_t ov;
                #pragma unroll
                for (int r = 0; r < 4; r++)
                    ov[r] = (__bf16)((acc[0][im][in_][r] + bb) * QSC);
                *reinterpret_cast<bf4_t*>(
                    Qo + ((size_t)(b * Hh + h) * Dd + d) * Tt + t0) = ov;
            }
            // K (scalar [bh][t][d] stores)
            {
                float bb = bk[gc];
                #pragma unroll
                for (int r = 0; r < 4; r++)
                    Ko[((size_t)(b * Hh + h) * Tt + t0 + r) * Dd + d] =
                        (__bf16)(acc[1][im][in_][r] + bb);
            }
            // V
            {
                float bb = bv[gc];
                bf4_t ov;
                #pragma unroll
                for (int r = 0; r < 4; r++)
                    ov[r] = (__bf16)(acc[2][im][in_][r] + bb);
                *reinterpret_cast<bf4_t*>(
                    Vo + ((size_t)(b * Hh + h) * Dd + d) * Tt + t0) = ov;
            }
        }
    }
}

// ---------------------------------------------------------------- out GEMM
// 64x128 tile, counted-vmcnt dbuf (same verified loop shape as qkv).
// grid (8,64) XCD-swizzled = 512 blocks = 2/CU. 6 loads/iter -> vmcnt(6).
__global__ __launch_bounds__(256) void gemm_out_kernel(
    const __bf16* __restrict__ A, const __bf16* __restrict__ Bt,
    const float* __restrict__ bias, float* __restrict__ out)
{
    alignas(16) __shared__ __bf16 As[2][64 * 64];    // 16KB
    alignas(16) __shared__ __bf16 Bs[2][128 * 64];   // 32KB

    // 512 blocks: XCD j gets by-range [j*8, j*8+8).
    int lin = blockIdx.x + 8 * blockIdx.y;          // 0..511
    int swz = (lin & 7) * 64 + (lin >> 3);
    int bx = swz & 7, by = swz >> 3;

    int tid  = threadIdx.x;
    int lane = tid & 63;
    int quad = lane >> 4;
    int l16  = lane & 15;
    int wave = tid >> 6;
    int wm   = wave >> 1, wn = wave & 1;

    f4_t acc[2][4];
    #pragma unroll
    for (int i = 0; i < 2; i++)
        #pragma unroll
        for (int j = 0; j < 4; j++)
            acc[i][j] = f4_t{0.f, 0.f, 0.f, 0.f};

    auto STAGE = [&](int kt, int pb) {
        #pragma unroll
        for (int i = 0; i < 2; i++) {
            int c   = tid + 256 * i;
            int row = c >> 3, j = c & 7;
            ASYNC16(A + (size_t)(by * 64 + row) * 1024 + kt + ((j ^ (row & 7)) * 8),
                    &As[pb][c * 8]);
        }
        #pragma unroll
        for (int i = 0; i < 4; i++) {
            int c   = tid + 256 * i;
            int row = c >> 3, j = c & 7;
            ASYNC16(Bt + (size_t)(bx * 128 + row) * 1024 + kt + ((j ^ (row & 7)) * 8),
                    &Bs[pb][c * 8]);
        }
    };

    auto COMPUTE = [&](int pb) {
        bf8_t af[2][2], bfr[2][4];
        #pragma unroll
        for (int c = 0; c < 2; c++) {
            #pragma unroll
            for (int im = 0; im < 2; im++) {
                int row = wm * 32 + im * 16 + l16;
                af[c][im] = *reinterpret_cast<const bf8_t*>(
                    &As[pb][row * 64 + (((c * 4 + quad) ^ (row & 7)) * 8)]);
            }
            #pragma unroll
            for (int in_ = 0; in_ < 4; in_++) {
                int row = wn * 64 + in_ * 16 + l16;
                bfr[c][in_] = *reinterpret_cast<const bf8_t*>(
                    &Bs[pb][row * 64 + (((c * 4 + quad) ^ (row & 7)) * 8)]);
            }
        }
        #pragma unroll
        for (int c = 0; c < 2; c++)
            #pragma unroll
            for (int im = 0; im < 2; im++)
                #pragma unroll
                for (int in_ = 0; in_ < 4; in_++)
                    acc[im][in_] = __builtin_amdgcn_mfma_f32_16x16x32_bf16(
                        af[c][im], bfr[c][in_], acc[im][in_], 0, 0, 0);
    };

    // prologue: tile 0 -> buf0, full drain
    STAGE(0, 0);
    asm volatile("s_waitcnt vmcnt(0)" ::: "memory");
    __builtin_amdgcn_s_barrier();
    __builtin_amdgcn_sched_barrier(0);

    for (int t = 0; t < 15; ++t) {
        int cur = t & 1;
        STAGE((t + 1) * 64, cur ^ 1);               // 6 loads, not drained
        asm volatile("s_waitcnt vmcnt(6)" ::: "memory");  // prev tile's done
        __builtin_amdgcn_s_barrier();
        __builtin_amdgcn_sched_barrier(0);
        COMPUTE(cur);
        asm volatile("s_waitcnt lgkmcnt(0)" ::: "memory");
        __builtin_amdgcn_s_barrier();               // reads done before overwrite
        __builtin_amdgcn_sched_barrier(0);
    }
    // last tile (t=15, buf1): staged at t=14
    asm volatile("s_waitcnt vmcnt(0)" ::: "memory");
    __builtin_amdgcn_s_barrier();
    __builtin_amdgcn_sched_barrier(0);
    COMPUTE(1);

    // epilogue: row-major f32 + bias
    #pragma unroll
    for (int im = 0; im < 2; im++) {
        #pragma unroll
        for (int in_ = 0; in_ < 4; in_++) {
            int gc  = bx * 128 + wn * 64 + in_ * 16 + l16;
            float bb = bias[gc];
            int gr0 = by * 64 + wm * 32 + im * 16 + quad * 4;
            #pragma unroll
            for (int r = 0; r < 4; r++)
                out[(size_t)(gr0 + r) * 1024 + gc] = acc[im][in_][r] + bb;
        }
    }
}

// ---------------------------------------------------------------- flash attn
// Frozen (round-10). 1D grid (512), head-grouped XCD decode: XCD j = id&7
// owns heads [4j,4j+4) -> per-XCD K/V+Q ~3MB L2-resident (FETCH 14.4MB).
// 512 thr = 8 waves x 16-row q-strips, 64-key tiles, dbuf LDS, reg
// prefetch, u64 bitmask, ones-MFMA l_i, setprio.
__global__ __launch_bounds__(512, 4) void flash_kernel(
    const __bf16* __restrict__ Qb, const __bf16* __restrict__ Kb,
    const __bf16* __restrict__ Vb, const unsigned* __restrict__ Mbits,
    __bf16* __restrict__ Zb)
{
    alignas(16) __shared__ __bf16 Ks[2][64 * 64];   // swizzled, 8KB each
    alignas(16) __shared__ __bf16 Vs[2][64 * 64];
    alignas(16) __shared__ __bf16 Ps[8 * 16 * 72];  // per-wave P^T, 18KB

    int tid  = threadIdx.x;
    int lane = tid & 63;
    int wave = tid >> 6;
    int quad = lane >> 4;
    int l16  = lane & 15;

    // head-grouped XCD decode: xcd = id&7 -> heads [4*xcd, 4*xcd+4)
    int id  = blockIdx.x;           // 0..511
    int xcd = id & 7;
    int idx = id >> 3;              // 0..63
    int hb  = xcd * 4 + (idx >> 4); // 0..31
    int qx  = idx & 15;
    int b = hb >> 4, h = hb & 15;
    int bh = hb;
    int qrow = qx * 128 + wave * 16;

    int srow = tid >> 3, sj = tid & 7;
    const __bf16* kgp = Kb + ((size_t)bh * Tt + srow) * Dd + ((sj ^ (srow & 7)) * 8);
    const __bf16* vgp = Vb + ((size_t)bh * Dd + srow) * Tt + ((sj ^ (srow & 7)) * 8);
    const int sdst = tid * 8;

    // Q from [bh][d][t]: lane l16 = query row qrow+l16, 8 d-values per chunk.
    bf8_t qf[2];
    #pragma unroll
    for (int c = 0; c < 2; c++)
        #pragma unroll
        for (int j = 0; j < 8; j++)
            qf[c][j] = Qb[((size_t)bh * Dd + c * 32 + quad * 8 + j) * Tt
                          + qrow + l16];

    // ones-fragment for the l_i row-sum MFMA (A = all-ones 16x32 tile)
    bf8_t ones;
    #pragma unroll
    for (int i = 0; i < 8; i++) ones[i] = (__bf16)1.0f;

    // bitmask row for this lane's query: 64 words/row, u64 per 64-key tile
    const unsigned* bmp = Mbits + ((size_t)b * Tt + qrow + l16) * 64;

    f4_t lacc = f4_t{0.f, 0.f, 0.f, 0.f};
    f4_t o[4];
    #pragma unroll
    for (int d = 0; d < 4; d++) o[d] = f4_t{0.f, 0.f, 0.f, 0.f};

    __bf16* pw = Ps + wave * 16 * 72;

    // prime: tile 0 into regs
    bf8_t kreg = *reinterpret_cast<const bf8_t*>(kgp);
    bf8_t vreg = *reinterpret_cast<const bf8_t*>(vgp);
    unsigned long long mreg = *reinterpret_cast<const unsigned long long*>(bmp);

    for (int kt = 0; kt < Tt; kt += 64) {
        int par = (kt >> 6) & 1;
        *reinterpret_cast<bf8_t*>(&Ks[par][sdst]) = kreg;
        *reinterpret_cast<bf8_t*>(&Vs[par][sdst]) = vreg;
        // per-n 4-bit nibbles for this lane's quad, captured before reload
        unsigned nib[4];
        #pragma unroll
        for (int n = 0; n < 4; n++)
            nib[n] = (unsigned)(mreg >> (n * 16 + quad * 4)) & 0xFu;
        __syncthreads();

        // prefetch next tile (issued after barrier -> not drained by it)
        int ktn = (kt + 64 < Tt) ? kt + 64 : 0;
        kreg = *reinterpret_cast<const bf8_t*>(kgp + (size_t)ktn * Dd);
        vreg = *reinterpret_cast<const bf8_t*>(vgp + ktn);
        mreg = *reinterpret_cast<const unsigned long long*>(bmp + (ktn >> 5));

        // S^T = K Q^T : 4 key-subtiles x 2 d-chunks
        f4_t s[4];
        #pragma unroll
        for (int n = 0; n < 4; n++) s[n] = f4_t{0.f, 0.f, 0.f, 0.f};
        __builtin_amdgcn_s_setprio(1);
        #pragma unroll
        for (int c = 0; c < 2; c++)
            #pragma unroll
            for (int n = 0; n < 4; n++) {
                int krow = n * 16 + l16;
                bf8_t kf = *reinterpret_cast<const bf8_t*>(
                    &Ks[par][krow * 64 + (((c * 4 + quad) ^ (krow & 7)) * 8)]);
                s[n] = __builtin_amdgcn_mfma_f32_16x16x32_bf16(kf, qf[c], s[n], 0, 0, 0);
            }
        __builtin_amdgcn_s_setprio(0);

        // p = mask-bit ? exp2(s) : 0; P^T -> LDS (row-sum via MFMA below)
        #pragma unroll
        for (int n = 0; n < 4; n++) {
            bf4_t pv4;
            #pragma unroll
            for (int r = 0; r < 4; r++) {
                float p = (nib[n] & (1u << r)) ? EXP2F(s[n][r]) : 0.f;
                pv4[r] = (__bf16)p;
            }
            *reinterpret_cast<bf4_t*>(&pw[l16 * 72 + n * 16 + quad * 4]) = pv4;
        }

        // O^T += V^T @ P^T over 64 keys (2 chunks); l_i += ones @ P^T
        __builtin_amdgcn_s_setprio(1);
        #pragma unroll
        for (int c = 0; c < 2; c++) {
            bf8_t pf = *reinterpret_cast<const bf8_t*>(
                &pw[l16 * 72 + c * 32 + quad * 8]);
            lacc = __builtin_amdgcn_mfma_f32_16x16x32_bf16(ones, pf, lacc, 0, 0, 0);
            #pragma unroll
            for (int ds = 0; ds < 4; ds++) {
                int vrow = ds * 16 + l16;
                bf8_t vf = *reinterpret_cast<const bf8_t*>(
                    &Vs[par][vrow * 64 + (((c * 4 + quad) ^ (vrow & 7)) * 8)]);
                o[ds] = __builtin_amdgcn_mfma_f32_16x16x32_bf16(vf, pf, o[ds], 0, 0, 0);
            }
        }
        __builtin_amdgcn_s_setprio(0);
        // no trailing barrier: next iter writes the other buffer.
    }

    // lacc rows are all identical (ones-fragment): lacc[0] = sum_k P[k][q=l16]
    float inv = 1.f / fmaxf(lacc[0], 1e-30f);
    size_t zrow = ((size_t)b * Tt + qrow + l16) * 1024 + h * 64;
    #pragma unroll
    for (int ds = 0; ds < 4; ds++) {
        bf4_t ov;
        #pragma unroll
        for (int r = 0; r < 4; r++) ov[r] = (__bf16)(o[ds][r] * inv);
        *reinterpret_cast<bf4_t*>(Zb + zrow + ds * 16 + quad * 4) = ov;
    }
}

// ---------------------------------------------------------------- launch
extern "C" void kernel_launch(void* const* d_in, const int* in_sizes, int n_in,
                              void* d_out, int out_size, void* d_ws, size_t ws_size,
                              hipStream_t stream)
{
    (void)in_sizes; (void)n_in; (void)out_size; (void)ws_size;

    const float* embed = (const float*)d_in[0];
    const int*   mask  = (const int*)d_in[1];
    const float* Wq = (const float*)d_in[2];
    const float* bq = (const float*)d_in[3];
    const float* Wk = (const float*)d_in[4];
    const float* bk = (const float*)d_in[5];
    const float* Wv = (const float*)d_in[6];
    const float* bv = (const float*)d_in[7];
    const float* Wz = (const float*)d_in[8];
    const float* bz = (const float*)d_in[9];
    float* out = (float*)d_out;

    char* ws = (char*)d_ws;
    const size_t MB = (size_t)1024 * 1024;
    __bf16*   WqT = (__bf16*)(ws + 0 * MB);
    __bf16*   WkT = (__bf16*)(ws + 2 * MB);
    __bf16*   WvT = (__bf16*)(ws + 4 * MB);
    __bf16*   WzT = (__bf16*)(ws + 6 * MB);
    __bf16*   Eb  = (__bf16*)(ws + 8 * MB);
    __bf16*   Qb  = (__bf16*)(ws + 16 * MB);
    __bf16*   Kb  = (__bf16*)(ws + 24 * MB);
    __bf16*   Vb  = (__bf16*)(ws + 32 * MB);
    __bf16*   Zb  = (__bf16*)(ws + 40 * MB);
    unsigned* Mb  = (unsigned*)(ws + 48 * MB);   // bitmask, 1MB -> total 49MB

    prep_kernel<<<dim3(6144), 256, 0, stream>>>(embed, mask, Wq, Wk, Wv, Wz,
                                                WqT, WkT, WvT, WzT, Eb, Mb);
    gemm_qkv_fused<<<dim3(256), 512, 0, stream>>>(Eb, WqT, WkT, WvT,
                                                  bq, bk, bv, Qb, Kb, Vb);
    flash_kernel<<<dim3(512), 512, 0, stream>>>(Qb, Kb, Vb, Mb, Zb);
    gemm_out_kernel<<<dim3(8, 64), 256, 0, stream>>>(Zb, WzT, bz, out);
}